// Round 1
// baseline (634.203 us; speedup 1.0000x reference)
//
#include <hip/hip_runtime.h>

// LateralInhibitionLIFCell: one block per row, winner-take-all lateral inhibition.
// Traffic: 3 fp32 reads + 3 fp32 writes of [4096, 8192] = ~805 MB -> memory-bound,
// ~128 us floor at 6.3 TB/s.

constexpr int B = 4096;
constexpr int N = 8192;
constexpr int BLOCK = 256;
constexpr int CHUNKS = N / (BLOCK * 4);  // 8 float4 chunks per thread

#define NEG_FLT_MAX (-3.402823466e38f)

__device__ __forceinline__ void combine_argmax(float& bv, int& bi, float ov, int oi) {
    // first-max semantics: strictly greater wins; on tie, smaller index wins
    if (ov > bv || (ov == bv && oi < bi)) { bv = ov; bi = oi; }
}

__global__ __launch_bounds__(BLOCK) void lif_wta_kernel(
    const float* __restrict__ x_in,
    const float* __restrict__ v_in,
    const float* __restrict__ i_in,
    float* __restrict__ z_out,
    float* __restrict__ v_out,
    float* __restrict__ i_out)
{
    const int row = blockIdx.x;
    const int tid = threadIdx.x;
    const size_t base = (size_t)row * N;

    const float4* x4 = reinterpret_cast<const float4*>(x_in + base);
    const float4* v4 = reinterpret_cast<const float4*>(v_in + base);
    const float4* c4 = reinterpret_cast<const float4*>(i_in + base);
    float4* z4 = reinterpret_cast<float4*>(z_out + base);
    float4* o4 = reinterpret_cast<float4*>(v_out + base);
    float4* i4 = reinterpret_cast<float4*>(i_out + base);

    float4 vn[CHUNKS];             // v_new kept for the (rare) no-spike rows
    float best_val = NEG_FLT_MAX;
    int   best_idx = 0x7fffffff;

#pragma unroll
    for (int k = 0; k < CHUNKS; ++k) {
        const int c = tid + k * BLOCK;   // float4 chunk index (coalesced)
        const float4 xx = x4[c];
        const float4 vv = v4[c];
        const float4 ii = c4[c];
        float4 in4, zz;
        const int e0 = c * 4;

        // Exact per-op rounding (__*_rn) to match numpy fp32 bit-for-bit:
        // z is binary and the argmax winner swings v_out by 5.0, so ulp drift
        // from FMA contraction can blow past the 0.1 absmax threshold.
#define LIF_ELEM(f, j)                                                            \
        {                                                                         \
            float inew = __fadd_rn(ii.f, __fmul_rn(0.5f, __fsub_rn(xx.f, ii.f))); \
            float vnew = __fadd_rn(vv.f, __fmul_rn(0.5f, __fsub_rn(inew, vv.f))); \
            in4.f = inew;                                                         \
            vn[k].f = vnew;                                                       \
            if (vnew >= 1.0f) {                                                   \
                zz.f = 1.0f;                                                      \
                /* ascending-index scan: strict > keeps first max */              \
                if (vnew > best_val) { best_val = vnew; best_idx = e0 + (j); }    \
            } else {                                                             \
                zz.f = 0.0f;                                                      \
            }                                                                     \
        }
        LIF_ELEM(x, 0)
        LIF_ELEM(y, 1)
        LIF_ELEM(z, 2)
        LIF_ELEM(w, 3)
#undef LIF_ELEM

        z4[c] = zz;
        i4[c] = in4;
    }

    // --- block-wide argmax reduction (64-lane wave shuffle, then LDS) ---
#pragma unroll
    for (int off = 32; off > 0; off >>= 1) {
        float ov = __shfl_down(best_val, off);
        int   oi = __shfl_down(best_idx, off);
        combine_argmax(best_val, best_idx, ov, oi);
    }

    __shared__ float s_val[BLOCK / 64];
    __shared__ int   s_idx[BLOCK / 64];
    __shared__ float s_bval;
    __shared__ int   s_bidx;

    const int wave = tid >> 6;
    const int lane = tid & 63;
    if (lane == 0) { s_val[wave] = best_val; s_idx[wave] = best_idx; }
    __syncthreads();
    if (tid == 0) {
        float bv = s_val[0]; int bi = s_idx[0];
#pragma unroll
        for (int w = 1; w < BLOCK / 64; ++w) combine_argmax(bv, bi, s_val[w], s_idx[w]);
        s_bval = bv; s_bidx = bi;
    }
    __syncthreads();
    const float row_best = s_bval;
    const int   winner   = s_bidx;

    // --- v_out write ---
    if (row_best >= 1.0f) {
        // Row has >=1 spike: winner gets V_RESET (it spiked), everyone else -5.
        // No dependence on stored v_new.
#pragma unroll
        for (int k = 0; k < CHUNKS; ++k) {
            const int c = tid + k * BLOCK;
            const int e0 = c * 4;
            float4 o;
            o.x = (e0     == winner) ? 0.0f : -5.0f;
            o.y = (e0 + 1 == winner) ? 0.0f : -5.0f;
            o.z = (e0 + 2 == winner) ? 0.0f : -5.0f;
            o.w = (e0 + 3 == winner) ? 0.0f : -5.0f;
            o4[c] = o;
        }
    } else {
        // No spikes anywhere in the row: v_out = v_new (no resets happened).
#pragma unroll
        for (int k = 0; k < CHUNKS; ++k) {
            o4[tid + k * BLOCK] = vn[k];
        }
    }
}

extern "C" void kernel_launch(void* const* d_in, const int* in_sizes, int n_in,
                              void* d_out, int out_size, void* d_ws, size_t ws_size,
                              hipStream_t stream) {
    const float* x = (const float*)d_in[0];
    const float* v = (const float*)d_in[1];
    const float* i = (const float*)d_in[2];

    float* out   = (float*)d_out;
    float* z_out = out;
    float* v_out = out + (size_t)B * N;
    float* i_out = out + 2 * (size_t)B * N;

    lif_wta_kernel<<<B, BLOCK, 0, stream>>>(x, v, i, z_out, v_out, i_out);
}